// Round 20
// baseline (105.697 us; speedup 1.0000x reference)
//
#include <hip/hip_runtime.h>

typedef _Float16 f16;
typedef _Float16 f16x4 __attribute__((ext_vector_type(4)));
typedef _Float16 f16x8 __attribute__((ext_vector_type(8)));
typedef __fp16 fp16x2 __attribute__((ext_vector_type(2)));
typedef float f32x4 __attribute__((ext_vector_type(4)));

static __device__ __forceinline__ f32x4 mfma_k32(f16x8 a, f16x8 b, f32x4 c) {
  return __builtin_amdgcn_mfma_f32_16x16x32_f16(a, b, c, 0, 0, 0);
}
// async global->LDS, 16B/lane; LDS dest = wave-uniform base + lane*16
static __device__ __forceinline__ void gll16(const f16* g, f16* l) {
  __builtin_amdgcn_global_load_lds(
      (const __attribute__((address_space(1))) void*)g,
      (__attribute__((address_space(3))) void*)l, 16, 0, 0);
}

#define BN 2048    // sequence length
#define CC 512     // channels
#define NHD 64     // head dim
#define MROWS 8192 // B*N
#define SLAB ((size_t)32 * BN * NHD)  // one of Q/K/V: 4,194,304 f16
#define CH 64      // keys per LDS chunk
// Q scale = HD^-0.5 * log2(e): scores land in log2-domain -> exp2f direct.
#define QSCALE 0.1803368801111204f

// ---------------------------------------------------------------------------
// f32 -> f16 pre-convert: X (8192x512), Wqkv (1536x512), Wproj (512x512).
// ---------------------------------------------------------------------------
__global__ __launch_bounds__(256)
void cvt_f16(const float* __restrict__ X, const float* __restrict__ Wq,
             const float* __restrict__ Wp, f16* __restrict__ x16,
             f16* __restrict__ wq16, f16* __restrict__ wp16) {
  const int idx = blockIdx.x * 256 + threadIdx.x;
  const int stride = gridDim.x * 256;
  for (int i = idx; i < (MROWS * CC) / 4; i += stride) {
    float4 v = ((const float4*)X)[i];
    f16x4 h = {(f16)v.x, (f16)v.y, (f16)v.z, (f16)v.w};
    ((f16x4*)x16)[i] = h;
  }
  for (int i = idx; i < (3 * CC * CC) / 4; i += stride) {
    float4 v = ((const float4*)Wq)[i];
    f16x4 h = {(f16)v.x, (f16)v.y, (f16)v.z, (f16)v.w};
    ((f16x4*)wq16)[i] = h;
  }
  for (int i = idx; i < (CC * CC) / 4; i += stride) {
    float4 v = ((const float4*)Wp)[i];
    f16x4 h = {(f16)v.x, (f16)v.y, (f16)v.z, (f16)v.w};
    ((f16x4*)wp16)[i] = h;
  }
}

// ---------------------------------------------------------------------------
// QKV GEMM, 128x64 tiles -> grid 1536 (~5-6 blocks/CU: latency hidden by
// TLP, the session-proven fix; R18's dbuf attempt was not). LDS 29.4 KB.
// XCD-bijective swizzle: each XCD owns 8 contiguous mt rows (A-panel L2
// reuse). N=64 tile == one head's full hd slice -> V epilogue single-phase.
// Same slot-XOR gll staging; bitwise-identical accumulation order.
// ---------------------------------------------------------------------------
__global__ __launch_bounds__(256)
void qkv_gemm(const f16* __restrict__ X, const f16* __restrict__ W,
              f16* __restrict__ qkv) {
  __shared__ __align__(16) f16 As[128 * 32];
  __shared__ __align__(16) f16 Bs[64 * 32];
  __shared__ __align__(16) f16 ep[64 * 136];
  const int t = threadIdx.x;
  const int lane = t & 63, wave = t >> 6;
  const int wr = wave >> 1, wc = wave & 1;
  const int bid = blockIdx.x;
  const int wg = (bid & 7) * 192 + (bid >> 3);  // bijective XCD swizzle
  const int mt = wg / 24, nt = wg % 24;
  const int m0 = mt * 128, n0 = nt * 64;
  const int grp = lane >> 4, lid = lane & 15;

  const int gslot = (lane & 3) ^ ((lane >> 2) & 3);
  const int ga0 = (m0 + wave * 32 + (lane >> 2)) * CC + gslot * 8;
  const int gb0 = (n0 + wave * 16 + (lane >> 2)) * CC + gslot * 8;
  f16* const ldsA = As + wave * 1024;
  f16* const ldsB = Bs + wave * 512;

  const int abase = wr * 2048 + lid * 32 + (grp ^ (lid & 3)) * 8;
  const int bbase = wc * 1024 + lid * 32 + (grp ^ (lid & 3)) * 8;

  const f32x4 zf = {0.f, 0.f, 0.f, 0.f};
  f32x4 acc[4][2];
#pragma unroll
  for (int i = 0; i < 4; i++)
#pragma unroll
    for (int j = 0; j < 2; j++) acc[i][j] = zf;

  for (int k0 = 0; k0 < CC; k0 += 32) {
    gll16(X + ga0 + k0, ldsA);
    gll16(X + ga0 + 16 * CC + k0, ldsA + 512);
    gll16(W + gb0 + k0, ldsB);
    __syncthreads();
    f16x8 af[4], bf[2];
#pragma unroll
    for (int mi = 0; mi < 4; mi++)
      af[mi] = *(const f16x8*)&As[abase + mi * 512];
#pragma unroll
    for (int ni = 0; ni < 2; ni++)
      bf[ni] = *(const f16x8*)&Bs[bbase + ni * 512];
#pragma unroll
    for (int mi = 0; mi < 4; mi++)
#pragma unroll
      for (int ni = 0; ni < 2; ni++)
        acc[mi][ni] = mfma_k32(af[mi], bf[ni], acc[mi][ni]);
    __syncthreads();
  }

  const int s = n0 >> 9;           // 0:Q 1:K 2:V (uniform per block)
  const int h = (n0 & 511) >> 6;   // head (tile = full hd slice of h)
  const int b = m0 >> 11;
  const int nbase = m0 & 2047;     // within-sequence token base
  if (s == 2) {
    // V: single-phase [d][pos] transpose (key-permuted) -> coalesced stores
#pragma unroll
    for (int mi = 0; mi < 4; mi++) {
      int m_local = wr * 64 + mi * 16 + grp * 4;
      int pos = (m_local & ~31) | (grp << 3) | ((mi & 1) << 2);
#pragma unroll
      for (int ni = 0; ni < 2; ni++) {
        int d = wc * 32 + ni * 16 + lid;
        f16x4 pk = {(f16)acc[mi][ni][0], (f16)acc[mi][ni][1],
                    (f16)acc[mi][ni][2], (f16)acc[mi][ni][3]};
        *(f16x4*)&ep[d * 136 + pos] = pk;
      }
    }
    __syncthreads();
#pragma unroll
    for (int u = 0; u < 4; ++u) {
      int unit = t + u * 256;
      int drow = unit >> 4, seg = unit & 15;
      f16x8 v = *(const f16x8*)&ep[drow * 136 + seg * 8];
      *(f16x8*)&qkv[2 * SLAB + ((size_t)((b * 8 + h) * 64 + drow)) * BN +
                    nbase + seg * 8] = v;
    }
  } else {
    // Q/K: 2-phase [token][d] transpose -> coalesced f16x8 row stores
    const float scale = (s == 0) ? QSCALE : 1.0f;
#pragma unroll
    for (int ph = 0; ph < 2; ++ph) {
      if (wr == ph) {
#pragma unroll
        for (int mi = 0; mi < 4; mi++)
#pragma unroll
          for (int ni = 0; ni < 2; ni++)
#pragma unroll
            for (int i = 0; i < 4; i++)
              ep[(mi * 16 + grp * 4 + i) * 72 + wc * 32 + ni * 16 + lid] =
                  (f16)(acc[mi][ni][i] * scale);
      }
      __syncthreads();
#pragma unroll
      for (int u = 0; u < 2; ++u) {
        int unit = t + u * 256;
        int row = unit >> 3, seg = unit & 7;
        int n = nbase + ph * 64 + row;
        f16x8 v = *(const f16x8*)&ep[row * 72 + seg * 8];
        *(f16x8*)&qkv[(size_t)s * SLAB +
                      ((size_t)((b * 8 + h) * BN + n)) * 64 + seg * 8] = v;
      }
      __syncthreads();
    }
  }
}

// ---------------------------------------------------------------------------
// Flash attention (R18/R19 exact: K=32 PV, 18 MFMA/chunk, 0 bank conflicts,
// issue-saturated). Fixed-m softmax; gll staging with pre-swizzled source;
// dbuf 32 KB; grid 1024; XCD-pinned heads.
// ---------------------------------------------------------------------------
__global__ __launch_bounds__(256)
void attn(const f16* __restrict__ qkv, f16* __restrict__ O) {
  __shared__ __align__(16) char smem[32768];

  const int bh = blockIdx.x & 31;  // XCD = bh % 8
  const int qb = blockIdx.x >> 5;  // 32 q-blocks of 64 rows
  const f16* Q = qkv + (size_t)bh * BN * NHD;
  const f16* K = qkv + SLAB + (size_t)bh * BN * NHD;
  const f16* VT = qkv + 2 * SLAB + (size_t)bh * (size_t)NHD * BN;  // (hd, pos)
  const int t = threadIdx.x, lane = t & 63, wave = t >> 6;
  const int grp = lane >> 4, qv = lane & 15;
  const int qrow = qb * 64 + wave * 16 + qv;
  const int xr = (qv & 7) << 4;

  // read-address bases; V bases alias these at +16384
  char* const kaddr0 = smem + qv * 128 + ((grp * 16) ^ xr);
  char* const kaddr1 = smem + qv * 128 + ((grp * 16 + 64) ^ xr);

  // gll staging: pre-swizzled global col (l&7)^(l>>3); linear LDS write
  const int srow = wave * 16 + (lane >> 3);
  const int scol = (lane & 7) ^ (lane >> 3);
  const int lo_k0 = srow * NHD + scol * 8;
  const int lo_k1 = (srow + 8) * NHD + scol * 8;
  const int lo_v0 = srow * BN + scol * 8;
  const int lo_v1 = (srow + 8) * BN + scol * 8;
  f16* const dK = (f16*)(smem + wave * 2048);
  f16* const dV = (f16*)(smem + 16384 + wave * 2048);

  f16x8 qf0 = *(const f16x8*)(Q + (size_t)qrow * NHD + grp * 8);
  f16x8 qf1 = *(const f16x8*)(Q + (size_t)qrow * NHD + 32 + grp * 8);

  const f32x4 zf = {0.f, 0.f, 0.f, 0.f};
  const f16x8 ones8 = {(f16)1.f, (f16)1.f, (f16)1.f, (f16)1.f,
                       (f16)1.f, (f16)1.f, (f16)1.f, (f16)1.f};
  f32x4 acc[4];
#pragma unroll
  for (int i = 0; i < 4; i++) acc[i] = zf;
  f32x4 lacc = zf;

  int koff = 0, voff = 0;
  gll16(K + lo_k0, dK);
  gll16(K + lo_k1, dK + 512);
  gll16(VT + lo_v0, dV);
  gll16(VT + lo_v1, dV + 512);
  koff = CH * NHD; voff = CH;
  __syncthreads();

#define ATTN_BODY(BUF, PF)                                                    \
  {                                                                           \
    if (PF) {                                                                 \
      gll16(K + koff + lo_k0, dK + (BUF ^ 1) * 4096);                         \
      gll16(K + koff + lo_k1, dK + (BUF ^ 1) * 4096 + 512);                   \
      gll16(VT + voff + lo_v0, dV + (BUF ^ 1) * 4096);                        \
      gll16(VT + voff + lo_v1, dV + (BUF ^ 1) * 4096 + 512);                  \
      koff += CH * NHD; voff += CH;                                           \
    }                                                                         \
    __builtin_amdgcn_s_setprio(1);                                            \
    _Pragma("unroll")                                                         \
    for (int kt2 = 0; kt2 < 2; kt2++) {                                       \
      char* const ka = kt2 ? kaddr1 : kaddr0;                                 \
      f16x8 k0a = *(const f16x8*)(kaddr0 + BUF * 8192 + kt2 * 4096);          \
      f16x8 k1a = *(const f16x8*)(kaddr1 + BUF * 8192 + kt2 * 4096);          \
      f32x4 st0 = mfma_k32(k1a, qf1, mfma_k32(k0a, qf0, zf));                 \
      f16x8 k0b = *(const f16x8*)(kaddr0 + BUF * 8192 + kt2 * 4096 + 2048);   \
      f16x8 k1b = *(const f16x8*)(kaddr1 + BUF * 8192 + kt2 * 4096 + 2048);   \
      f32x4 st1 = mfma_k32(k1b, qf1, mfma_k32(k0b, qf0, zf));                 \
      union { f16x8 w; fp16x2 h[4]; } up;                                     \
      up.h[0] = __builtin_amdgcn_cvt_pkrtz(exp2f(st0[0]), exp2f(st0[1]));     \
      up.h[1] = __builtin_amdgcn_cvt_pkrtz(exp2f(st0[2]), exp2f(st0[3]));     \
      up.h[2] = __builtin_amdgcn_cvt_pkrtz(exp2f(st1[0]), exp2f(st1[1]));     \
      up.h[3] = __builtin_amdgcn_cvt_pkrtz(exp2f(st1[2]), exp2f(st1[3]));     \
      f16x8 p8 = up.w;                                                        \
      lacc = mfma_k32(ones8, p8, lacc);                                       \
      _Pragma("unroll")                                                       \
      for (int dt = 0; dt < 4; dt++) {                                        \
        f16x8 v8 = *(const f16x8*)(ka + 16384 + BUF * 8192 + dt * 2048);      \
        acc[dt] = mfma_k32(v8, p8, acc[dt]);                                  \
      }                                                                       \
    }                                                                         \
    __builtin_amdgcn_s_setprio(0);                                            \
    __syncthreads();                                                          \
  }

  // 32 chunks: 15 unrolled pairs + final pair (last chunk: no prefetch)
  for (int p = 0; p < 15; ++p) {
    ATTN_BODY(0, 1)
    ATTN_BODY(1, 1)
  }
  ATTN_BODY(0, 1)
  ATTN_BODY(1, 0)
#undef ATTN_BODY

  // epilogue -> O (B,N,C) f16, vectorized 8B stores
  const int b = bh >> 3, h = bh & 7;
  float inv = 1.0f / lacc[0];
#pragma unroll
  for (int dt = 0; dt < 4; dt++) {
    f16x4 o = {(f16)(acc[dt][0] * inv), (f16)(acc[dt][1] * inv),
               (f16)(acc[dt][2] * inv), (f16)(acc[dt][3] * inv)};
    *(f16x4*)&O[((size_t)(b * BN + qrow)) * CC + h * NHD + dt * 16 + grp * 4] = o;
  }
}

// ---------------------------------------------------------------------------
// Output projection, 64x64 tiles -> grid 1024 (4 blocks/CU, LDS 8 KB).
// XCD-bijective swizzle for A-panel L2 reuse. Same gll+swizzle staging.
// ---------------------------------------------------------------------------
__global__ __launch_bounds__(256)
void proj_gemm(const f16* __restrict__ A, const f16* __restrict__ W,
               const float* __restrict__ bias, float* __restrict__ out) {
  __shared__ __align__(16) f16 As[64 * 32];
  __shared__ __align__(16) f16 Bs[64 * 32];
  const int t = threadIdx.x;
  const int lane = t & 63, wave = t >> 6;
  const int wr = wave >> 1, wc = wave & 1;
  const int bid = blockIdx.x;
  const int wg = (bid & 7) * 128 + (bid >> 3);  // bijective XCD swizzle
  const int mt = wg >> 3, nt = wg & 7;
  const int m0 = mt * 64, n0 = nt * 64;
  const int grp = lane >> 4, lid = lane & 15;

  const int gslot = (lane & 3) ^ ((lane >> 2) & 3);
  const int ga0 = (m0 + wave * 16 + (lane >> 2)) * CC + gslot * 8;
  const int gb0 = (n0 + wave * 16 + (lane >> 2)) * CC + gslot * 8;
  f16* const ldsA = As + wave * 512;
  f16* const ldsB = Bs + wave * 512;
  const int abase = wr * 1024 + lid * 32 + (grp ^ (lid & 3)) * 8;
  const int bbase = wc * 1024 + lid * 32 + (grp ^ (lid & 3)) * 8;

  const f32x4 zf = {0.f, 0.f, 0.f, 0.f};
  f32x4 acc[2][2];
#pragma unroll
  for (int i = 0; i < 2; i++)
#pragma unroll
    for (int j = 0; j < 2; j++) acc[i][j] = zf;

  for (int k0 = 0; k0 < CC; k0 += 32) {
    gll16(A + ga0 + k0, ldsA);
    gll16(W + gb0 + k0, ldsB);
    __syncthreads();
    f16x8 af[2], bf[2];
#pragma unroll
    for (int mi = 0; mi < 2; mi++)
      af[mi] = *(const f16x8*)&As[abase + mi * 512];
#pragma unroll
    for (int ni = 0; ni < 2; ni++)
      bf[ni] = *(const f16x8*)&Bs[bbase + ni * 512];
#pragma unroll
    for (int mi = 0; mi < 2; mi++)
#pragma unroll
      for (int ni = 0; ni < 2; ni++)
        acc[mi][ni] = mfma_k32(af[mi], bf[ni], acc[mi][ni]);
    __syncthreads();
  }
#pragma unroll
  for (int mi = 0; mi < 2; mi++) {
#pragma unroll
    for (int ni = 0; ni < 2; ni++) {
      int d = n0 + wc * 32 + ni * 16 + lid;
      float bv = bias[d];
#pragma unroll
      for (int i = 0; i < 4; i++) {
        int row = m0 + wr * 32 + mi * 16 + grp * 4 + i;
        out[(size_t)row * CC + d] = acc[mi][ni][i] + bv;
      }
    }
  }
}

extern "C" void kernel_launch(void* const* d_in, const int* in_sizes, int n_in,
                              void* d_out, int out_size, void* d_ws, size_t ws_size,
                              hipStream_t stream) {
  const float* x = (const float*)d_in[0];
  const float* w_qkv = (const float*)d_in[1];
  const float* w_proj = (const float*)d_in[2];
  const float* b_proj = (const float*)d_in[3];
  float* out = (float*)d_out;

  f16* qkv = (f16*)d_ws;                       // 3 slabs = 25.2 MB
  f16* Obuf = qkv + 3 * SLAB;                  // 8.4 MB (doubles as Xf16 home)
  f16* x16 = Obuf;                             // dead after qkv_gemm
  f16* wq16 = Obuf + (size_t)MROWS * CC;       // 1.5 MB
  f16* wp16 = wq16 + (size_t)3 * CC * CC;      // 0.5 MB

  cvt_f16<<<dim3(1024), dim3(256), 0, stream>>>(x, w_qkv, w_proj, x16, wq16, wp16);
  qkv_gemm<<<dim3(1536), dim3(256), 0, stream>>>(x16, wq16, qkv);
  attn<<<dim3(32 * 32), dim3(256), 0, stream>>>(qkv, Obuf);
  proj_gemm<<<dim3(1024), dim3(256), 0, stream>>>(Obuf, wp16, b_proj, out);
}

// Round 21
// 101.286 us; speedup vs baseline: 1.0436x; 1.0436x over previous
//
#include <hip/hip_runtime.h>

typedef _Float16 f16;
typedef _Float16 f16x4 __attribute__((ext_vector_type(4)));
typedef _Float16 f16x8 __attribute__((ext_vector_type(8)));
typedef __fp16 fp16x2 __attribute__((ext_vector_type(2)));
typedef float f32x4 __attribute__((ext_vector_type(4)));

static __device__ __forceinline__ f32x4 mfma_k32(f16x8 a, f16x8 b, f32x4 c) {
  return __builtin_amdgcn_mfma_f32_16x16x32_f16(a, b, c, 0, 0, 0);
}
// async global->LDS, 16B/lane; LDS dest = wave-uniform base + lane*16
static __device__ __forceinline__ void gll16(const f16* g, f16* l) {
  __builtin_amdgcn_global_load_lds(
      (const __attribute__((address_space(1))) void*)g,
      (__attribute__((address_space(3))) void*)l, 16, 0, 0);
}

#define BN 2048    // sequence length
#define CC 512     // channels
#define NHD 64     // head dim
#define MROWS 8192 // B*N
#define SLAB ((size_t)32 * BN * NHD)  // one of Q/K/V: 4,194,304 f16
#define CH 64      // keys per LDS chunk
#define EPAD 136   // ep LDS pad (mult of 8 f16 -> b128-aligned rows)
// Q scale = HD^-0.5 * log2(e): scores land in log2-domain -> exp2f direct.
#define QSCALE 0.1803368801111204f

// ---------------------------------------------------------------------------
// f32 -> f16 pre-convert: X (8192x512), Wqkv (1536x512), Wproj (512x512).
// ---------------------------------------------------------------------------
__global__ __launch_bounds__(256)
void cvt_f16(const float* __restrict__ X, const float* __restrict__ Wq,
             const float* __restrict__ Wp, f16* __restrict__ x16,
             f16* __restrict__ wq16, f16* __restrict__ wp16) {
  const int idx = blockIdx.x * 256 + threadIdx.x;
  const int stride = gridDim.x * 256;
  for (int i = idx; i < (MROWS * CC) / 4; i += stride) {
    float4 v = ((const float4*)X)[i];
    f16x4 h = {(f16)v.x, (f16)v.y, (f16)v.z, (f16)v.w};
    ((f16x4*)x16)[i] = h;
  }
  for (int i = idx; i < (3 * CC * CC) / 4; i += stride) {
    float4 v = ((const float4*)Wq)[i];
    f16x4 h = {(f16)v.x, (f16)v.y, (f16)v.z, (f16)v.w};
    ((f16x4*)wq16)[i] = h;
  }
  for (int i = idx; i < (CC * CC) / 4; i += stride) {
    float4 v = ((const float4*)Wp)[i];
    f16x4 h = {(f16)v.x, (f16)v.y, (f16)v.z, (f16)v.w};
    ((f16x4*)wp16)[i] = h;
  }
}

// ---------------------------------------------------------------------------
// QKV GEMM (measured-best config: 128x128 tiles, grid 768, single-buffered
// gll staging -- dbuf (R18) and 128x64 retile (R20) both regressed).
// [128][32] slot-XOR swizzle; epilogue via ep LDS transpose (coalesced
// f16x8 stores; V key-permuted for attn's b128 reads).
// ---------------------------------------------------------------------------
__global__ __launch_bounds__(256)
void qkv_gemm(const f16* __restrict__ X, const f16* __restrict__ W,
              f16* __restrict__ qkv) {
  __shared__ __align__(16) f16 As[128 * 32];
  __shared__ __align__(16) f16 Bs[128 * 32];
  __shared__ __align__(16) f16 ep[64 * EPAD];
  const int t = threadIdx.x;
  const int lane = t & 63, wave = t >> 6;
  const int wr = wave >> 1, wc = wave & 1;
  const int mt = blockIdx.x / 12, nt = blockIdx.x % 12;
  const int m0 = mt * 128, n0 = nt * 128;
  const int grp = lane >> 4, lid = lane & 15;

  const int srow = 32 * wave + (lane >> 2);
  const int gslot = (lane & 3) ^ ((lane >> 2) & 3);
  const int ga0 = (m0 + srow) * CC + gslot * 8;
  const int gb0 = (n0 + srow) * CC + gslot * 8;
  f16* const ldsA = As + wave * 1024;
  f16* const ldsB = Bs + wave * 1024;

  const int abase = wr * 2048 + lid * 32 + (grp ^ (lid & 3)) * 8;
  const int bbase = wc * 2048 + lid * 32 + (grp ^ (lid & 3)) * 8;

  const f32x4 zf = {0.f, 0.f, 0.f, 0.f};
  f32x4 acc[4][4];
#pragma unroll
  for (int i = 0; i < 4; i++)
#pragma unroll
    for (int j = 0; j < 4; j++) acc[i][j] = zf;

  for (int k0 = 0; k0 < CC; k0 += 32) {
    gll16(X + ga0 + k0, ldsA);
    gll16(X + ga0 + 16 * CC + k0, ldsA + 512);
    gll16(W + gb0 + k0, ldsB);
    gll16(W + gb0 + 16 * CC + k0, ldsB + 512);
    __syncthreads();
    f16x8 af[4], bf[4];
#pragma unroll
    for (int mi = 0; mi < 4; mi++)
      af[mi] = *(const f16x8*)&As[abase + mi * 512];
#pragma unroll
    for (int ni = 0; ni < 4; ni++)
      bf[ni] = *(const f16x8*)&Bs[bbase + ni * 512];
#pragma unroll
    for (int mi = 0; mi < 4; mi++)
#pragma unroll
      for (int ni = 0; ni < 4; ni++)
        acc[mi][ni] = mfma_k32(af[mi], bf[ni], acc[mi][ni]);
    __syncthreads();
  }

  const int s = n0 >> 9;  // uniform per block (nt 0-3: Q, 4-7: K, 8-11: V)
  const int b = m0 >> 11;
  const int nbase = m0 & 2047;  // within-sequence column base
  if (s == 2) {
    // V: 2-phase [d][pos] LDS transpose (key-permuted) -> coalesced stores
#pragma unroll
    for (int ph = 0; ph < 2; ++ph) {
      if (wc == ph) {
#pragma unroll
        for (int mi = 0; mi < 4; mi++) {
          int kloc = wr * 64 + mi * 16 + grp * 4;
          int pos = (kloc & ~31) | (grp << 3) | ((mi & 1) << 2);
#pragma unroll
          for (int ni = 0; ni < 4; ni++) {
            f16x4 pk = {(f16)acc[mi][ni][0], (f16)acc[mi][ni][1],
                        (f16)acc[mi][ni][2], (f16)acc[mi][ni][3]};
            *(f16x4*)&ep[(ni * 16 + lid) * EPAD + pos] = pk;
          }
        }
      }
      __syncthreads();
#pragma unroll
      for (int u = 0; u < 4; ++u) {
        int unit = t + u * 256;
        int row = unit >> 4, seg = unit & 15;
        int dg = n0 + ph * 64 + row;
        int h = (dg & 511) >> 6, hd = dg & 63;
        f16x8 v = *(const f16x8*)&ep[row * EPAD + seg * 8];
        *(f16x8*)&qkv[2 * SLAB + ((size_t)((b * 8 + h) * 64 + hd)) * BN +
                      nbase + seg * 8] = v;
      }
      __syncthreads();
    }
  } else {
    // Q/K: 2-phase [row][d] LDS transpose -> coalesced f16x8 row stores
    const float scale = (s == 0) ? QSCALE : 1.0f;
#pragma unroll
    for (int ph = 0; ph < 2; ++ph) {
      if (wr == ph) {
#pragma unroll
        for (int mi = 0; mi < 4; mi++)
#pragma unroll
          for (int ni = 0; ni < 4; ni++)
#pragma unroll
            for (int i = 0; i < 4; i++)
              ep[(mi * 16 + grp * 4 + i) * EPAD + wc * 64 + ni * 16 + lid] =
                  (f16)(acc[mi][ni][i] * scale);
      }
      __syncthreads();
#pragma unroll
      for (int u = 0; u < 4; ++u) {
        int unit = t + u * 256;
        int row = unit >> 4, seg = unit & 15;
        int row_g = m0 + ph * 64 + row;
        int n = row_g & 2047;
        int d_g = n0 + seg * 8;
        int h = (d_g & 511) >> 6, hd = d_g & 63;
        f16x8 v = *(const f16x8*)&ep[row * EPAD + seg * 8];
        *(f16x8*)&qkv[(size_t)s * SLAB +
                      ((size_t)((b * 8 + h) * BN + n)) * 64 + hd] = v;
      }
      __syncthreads();
    }
  }
}

// ---------------------------------------------------------------------------
// Flash attention (measured-best: K=32 PV). Key-permuted V layout = 16x16x32
// B-operand key order, so P8 = concat(cvt_pk(st0), cvt_pk(st1)) feeds one
// k32 MFMA per dt + one for l-sum: 18 MFMA issues/chunk. Fixed-m softmax;
// gll staging with pre-swizzled source; dbuf 32 KB; grid 1024; XCD-pinned.
// ---------------------------------------------------------------------------
__global__ __launch_bounds__(256)
void attn(const f16* __restrict__ qkv, f16* __restrict__ O) {
  __shared__ __align__(16) char smem[32768];

  const int bh = blockIdx.x & 31;  // XCD = bh % 8
  const int qb = blockIdx.x >> 5;  // 32 q-blocks of 64 rows
  const f16* Q = qkv + (size_t)bh * BN * NHD;
  const f16* K = qkv + SLAB + (size_t)bh * BN * NHD;
  const f16* VT = qkv + 2 * SLAB + (size_t)bh * (size_t)NHD * BN;  // (hd, pos)
  const int t = threadIdx.x, lane = t & 63, wave = t >> 6;
  const int grp = lane >> 4, qv = lane & 15;
  const int qrow = qb * 64 + wave * 16 + qv;
  const int xr = (qv & 7) << 4;

  // read-address bases; V bases alias these at +16384
  char* const kaddr0 = smem + qv * 128 + ((grp * 16) ^ xr);
  char* const kaddr1 = smem + qv * 128 + ((grp * 16 + 64) ^ xr);

  // gll staging: pre-swizzled global col (l&7)^(l>>3); linear LDS write
  const int srow = wave * 16 + (lane >> 3);
  const int scol = (lane & 7) ^ (lane >> 3);
  const int lo_k0 = srow * NHD + scol * 8;
  const int lo_k1 = (srow + 8) * NHD + scol * 8;
  const int lo_v0 = srow * BN + scol * 8;
  const int lo_v1 = (srow + 8) * BN + scol * 8;
  f16* const dK = (f16*)(smem + wave * 2048);
  f16* const dV = (f16*)(smem + 16384 + wave * 2048);

  f16x8 qf0 = *(const f16x8*)(Q + (size_t)qrow * NHD + grp * 8);
  f16x8 qf1 = *(const f16x8*)(Q + (size_t)qrow * NHD + 32 + grp * 8);

  const f32x4 zf = {0.f, 0.f, 0.f, 0.f};
  const f16x8 ones8 = {(f16)1.f, (f16)1.f, (f16)1.f, (f16)1.f,
                       (f16)1.f, (f16)1.f, (f16)1.f, (f16)1.f};
  f32x4 acc[4];
#pragma unroll
  for (int i = 0; i < 4; i++) acc[i] = zf;
  f32x4 lacc = zf;

  int koff = 0, voff = 0;
  gll16(K + lo_k0, dK);
  gll16(K + lo_k1, dK + 512);
  gll16(VT + lo_v0, dV);
  gll16(VT + lo_v1, dV + 512);
  koff = CH * NHD; voff = CH;
  __syncthreads();

#define ATTN_BODY(BUF, PF)                                                    \
  {                                                                           \
    if (PF) {                                                                 \
      gll16(K + koff + lo_k0, dK + (BUF ^ 1) * 4096);                         \
      gll16(K + koff + lo_k1, dK + (BUF ^ 1) * 4096 + 512);                   \
      gll16(VT + voff + lo_v0, dV + (BUF ^ 1) * 4096);                        \
      gll16(VT + voff + lo_v1, dV + (BUF ^ 1) * 4096 + 512);                  \
      koff += CH * NHD; voff += CH;                                           \
    }                                                                         \
    __builtin_amdgcn_s_setprio(1);                                            \
    _Pragma("unroll")                                                         \
    for (int kt2 = 0; kt2 < 2; kt2++) {                                       \
      char* const ka = kt2 ? kaddr1 : kaddr0;                                 \
      f16x8 k0a = *(const f16x8*)(kaddr0 + BUF * 8192 + kt2 * 4096);          \
      f16x8 k1a = *(const f16x8*)(kaddr1 + BUF * 8192 + kt2 * 4096);          \
      f32x4 st0 = mfma_k32(k1a, qf1, mfma_k32(k0a, qf0, zf));                 \
      f16x8 k0b = *(const f16x8*)(kaddr0 + BUF * 8192 + kt2 * 4096 + 2048);   \
      f16x8 k1b = *(const f16x8*)(kaddr1 + BUF * 8192 + kt2 * 4096 + 2048);   \
      f32x4 st1 = mfma_k32(k1b, qf1, mfma_k32(k0b, qf0, zf));                 \
      union { f16x8 w; fp16x2 h[4]; } up;                                     \
      up.h[0] = __builtin_amdgcn_cvt_pkrtz(exp2f(st0[0]), exp2f(st0[1]));     \
      up.h[1] = __builtin_amdgcn_cvt_pkrtz(exp2f(st0[2]), exp2f(st0[3]));     \
      up.h[2] = __builtin_amdgcn_cvt_pkrtz(exp2f(st1[0]), exp2f(st1[1]));     \
      up.h[3] = __builtin_amdgcn_cvt_pkrtz(exp2f(st1[2]), exp2f(st1[3]));     \
      f16x8 p8 = up.w;                                                        \
      lacc = mfma_k32(ones8, p8, lacc);                                       \
      _Pragma("unroll")                                                       \
      for (int dt = 0; dt < 4; dt++) {                                        \
        f16x8 v8 = *(const f16x8*)(ka + 16384 + BUF * 8192 + dt * 2048);      \
        acc[dt] = mfma_k32(v8, p8, acc[dt]);                                  \
      }                                                                       \
    }                                                                         \
    __builtin_amdgcn_s_setprio(0);                                            \
    __syncthreads();                                                          \
  }

  // 32 chunks: 15 unrolled pairs + final pair (last chunk: no prefetch)
  for (int p = 0; p < 15; ++p) {
    ATTN_BODY(0, 1)
    ATTN_BODY(1, 1)
  }
  ATTN_BODY(0, 1)
  ATTN_BODY(1, 0)
#undef ATTN_BODY

  // epilogue -> O (B,N,C) f16, vectorized 8B stores
  const int b = bh >> 3, h = bh & 7;
  float inv = 1.0f / lacc[0];
#pragma unroll
  for (int dt = 0; dt < 4; dt++) {
    f16x4 o = {(f16)(acc[dt][0] * inv), (f16)(acc[dt][1] * inv),
               (f16)(acc[dt][2] * inv), (f16)(acc[dt][3] * inv)};
    *(f16x4*)&O[((size_t)(b * BN + qrow)) * CC + h * NHD + dt * 16 + grp * 4] = o;
  }
}

// ---------------------------------------------------------------------------
// Output projection (measured-best: 64x128 tiles, 512 blocks, single-buf).
// ---------------------------------------------------------------------------
__global__ __launch_bounds__(256)
void proj_gemm(const f16* __restrict__ A, const f16* __restrict__ W,
               const float* __restrict__ bias, float* __restrict__ out) {
  __shared__ __align__(16) f16 As[64 * 32];
  __shared__ __align__(16) f16 Bs[128 * 32];
  const int t = threadIdx.x;
  const int lane = t & 63, wave = t >> 6;
  const int wr = wave >> 1, wc = wave & 1;
  const int mt = blockIdx.x >> 2, nt = blockIdx.x & 3;
  const int m0 = mt * 64, n0 = nt * 128;
  const int grp = lane >> 4, lid = lane & 15;

  const int gslot = (lane & 3) ^ ((lane >> 2) & 3);
  const int ga0 = (m0 + wave * 16 + (lane >> 2)) * CC + gslot * 8;
  const int gb0 = (n0 + wave * 32 + (lane >> 2)) * CC + gslot * 8;
  f16* const ldsA = As + wave * 512;
  f16* const ldsB = Bs + wave * 1024;
  const int abase = (wr * 32 + lid) * 32 + (grp ^ (lid & 3)) * 8;
  const int bbase = (wc * 64 + lid) * 32 + (grp ^ (lid & 3)) * 8;

  const f32x4 zf = {0.f, 0.f, 0.f, 0.f};
  f32x4 acc[2][4];
#pragma unroll
  for (int i = 0; i < 2; i++)
#pragma unroll
    for (int j = 0; j < 4; j++) acc[i][j] = zf;

  for (int k0 = 0; k0 < CC; k0 += 32) {
    gll16(A + ga0 + k0, ldsA);
    gll16(W + gb0 + k0, ldsB);
    gll16(W + gb0 + 16 * CC + k0, ldsB + 512);
    __syncthreads();
    f16x8 af[2], bf[4];
#pragma unroll
    for (int mi = 0; mi < 2; mi++)
      af[mi] = *(const f16x8*)&As[abase + mi * 512];
#pragma unroll
    for (int ni = 0; ni < 4; ni++)
      bf[ni] = *(const f16x8*)&Bs[bbase + ni * 512];
#pragma unroll
    for (int mi = 0; mi < 2; mi++)
#pragma unroll
      for (int ni = 0; ni < 4; ni++)
        acc[mi][ni] = mfma_k32(af[mi], bf[ni], acc[mi][ni]);
    __syncthreads();
  }
#pragma unroll
  for (int mi = 0; mi < 2; mi++) {
#pragma unroll
    for (int ni = 0; ni < 4; ni++) {
      int d = n0 + wc * 64 + ni * 16 + lid;
      float bv = bias[d];
#pragma unroll
      for (int i = 0; i < 4; i++) {
        int row = m0 + wr * 32 + mi * 16 + grp * 4 + i;
        out[(size_t)row * CC + d] = acc[mi][ni][i] + bv;
      }
    }
  }
}

extern "C" void kernel_launch(void* const* d_in, const int* in_sizes, int n_in,
                              void* d_out, int out_size, void* d_ws, size_t ws_size,
                              hipStream_t stream) {
  const float* x = (const float*)d_in[0];
  const float* w_qkv = (const float*)d_in[1];
  const float* w_proj = (const float*)d_in[2];
  const float* b_proj = (const float*)d_in[3];
  float* out = (float*)d_out;

  f16* qkv = (f16*)d_ws;                       // 3 slabs = 25.2 MB
  f16* Obuf = qkv + 3 * SLAB;                  // 8.4 MB (doubles as Xf16 home)
  f16* x16 = Obuf;                             // dead after qkv_gemm
  f16* wq16 = Obuf + (size_t)MROWS * CC;       // 1.5 MB
  f16* wp16 = wq16 + (size_t)3 * CC * CC;      // 0.5 MB

  cvt_f16<<<dim3(1024), dim3(256), 0, stream>>>(x, w_qkv, w_proj, x16, wq16, wp16);
  qkv_gemm<<<dim3(64 * 12), dim3(256), 0, stream>>>(x16, wq16, qkv);
  attn<<<dim3(32 * 32), dim3(256), 0, stream>>>(qkv, Obuf);
  proj_gemm<<<dim3(128 * 4), dim3(256), 0, stream>>>(Obuf, wp16, b_proj, out);
}